// Round 1
// baseline (663.495 us; speedup 1.0000x reference)
//
#include <hip/hip_runtime.h>

// ProtoCLR loss on MI355X.
// Pipeline: inv_norm -> label histogram -> scan -> counting-sort scatter ->
// per-class mean (deterministic, no float atomics) -> fused GEMM+LSE -> final.

constexpr int N_ROWS = 65536;
constexpr int D_DIM  = 256;
constexpr int C_CLS  = 256;
constexpr int TWO_N  = 2 * N_ROWS;
constexpr float EPS_NORM = 1e-12f;

// ---- workspace layout (bytes), all 16B aligned ----
constexpr size_t WS_HIST    = 0;                                   // int[256]
constexpr size_t WS_CURSOR  = 1024;                                // int[256]
constexpr size_t WS_LOSS    = 2048;                                // double[1]
constexpr size_t WS_OFFSETS = 4096;                                // int[257]
constexpr size_t WS_COUNTSF = 6144;                                // float[256]
constexpr size_t WS_INVNORM = 8192;                                // float[2N]
constexpr size_t WS_ORDER   = WS_INVNORM + sizeof(float) * TWO_N;  // int[2N]
constexpr size_t WS_MEANST  = WS_ORDER + sizeof(int) * TWO_N;      // float[D*C] transposed [d][c]

// 1 wave per row: lane loads float4, shuffle-reduce sum of squares.
__global__ __launch_bounds__(256)
void k_invnorm(const float* __restrict__ z1, const float* __restrict__ z2,
               float* __restrict__ inv_norm)
{
    const int wave = threadIdx.x >> 6;
    const int lane = threadIdx.x & 63;
    const int row  = blockIdx.x * 4 + wave;
    const float* src = (row < N_ROWS) ? (z1 + (size_t)row * D_DIM)
                                      : (z2 + (size_t)(row - N_ROWS) * D_DIM);
    const float4 v = reinterpret_cast<const float4*>(src)[lane];
    float s = v.x * v.x + v.y * v.y + v.z * v.z + v.w * v.w;
    #pragma unroll
    for (int off = 32; off; off >>= 1) s += __shfl_down(s, off, 64);
    if (lane == 0) {
        inv_norm[row] = 1.0f / fmaxf(sqrtf(s), EPS_NORM);
    }
}

__global__ __launch_bounds__(256)
void k_hist(const int* __restrict__ labels, int* __restrict__ hist)
{
    const int i = blockIdx.x * 256 + threadIdx.x;
    if (i < N_ROWS) atomicAdd(&hist[labels[i]], 1);
}

// single block: exclusive scan of 2*hist (labels duplicated for both views)
__global__ __launch_bounds__(256)
void k_scan(const int* __restrict__ hist, int* __restrict__ offsets,
            float* __restrict__ countsf)
{
    __shared__ int tmp[C_CLS];
    const int t = threadIdx.x;
    tmp[t] = hist[t] * 2;
    countsf[t] = (float)(hist[t] * 2);
    __syncthreads();
    if (t == 0) {
        int acc = 0;
        for (int c = 0; c < C_CLS; ++c) { offsets[c] = acc; acc += tmp[c]; }
        offsets[C_CLS] = acc;
    }
}

__global__ __launch_bounds__(256)
void k_scatter(const int* __restrict__ labels, const int* __restrict__ offsets,
               int* __restrict__ cursor, int* __restrict__ order)
{
    const int i = blockIdx.x * 256 + threadIdx.x;
    if (i < TWO_N) {
        const int lab = labels[(i < N_ROWS) ? i : (i - N_ROWS)];
        const int pos = offsets[lab] + atomicAdd(&cursor[lab], 1);
        order[pos] = i;
    }
}

// One block per class; thread = dim. Deterministic sum over that class's rows.
// Stores means TRANSPOSED: meansT[d][c] for coalesced GEMM B reads.
__global__ __launch_bounds__(256)
void k_means(const float* __restrict__ z1, const float* __restrict__ z2,
             const float* __restrict__ inv_norm, const int* __restrict__ order,
             const int* __restrict__ offsets, const float* __restrict__ countsf,
             float* __restrict__ meansT)
{
    const int c = blockIdx.x;
    const int d = threadIdx.x;
    const int s = offsets[c], e = offsets[c + 1];
    float acc = 0.0f;
    int idx = s;
    for (; idx + 8 <= e; idx += 8) {
        float part = 0.0f;
        #pragma unroll
        for (int u = 0; u < 8; ++u) {
            const int r = order[idx + u];
            const float* src = (r < N_ROWS) ? (z1 + (size_t)r * D_DIM)
                                            : (z2 + (size_t)(r - N_ROWS) * D_DIM);
            part += src[d] * inv_norm[r];
        }
        acc += part;
    }
    for (; idx < e; ++idx) {
        const int r = order[idx];
        const float* src = (r < N_ROWS) ? (z1 + (size_t)r * D_DIM)
                                        : (z2 + (size_t)(r - N_ROWS) * D_DIM);
        acc += src[d] * inv_norm[r];
    }
    meansT[(size_t)d * C_CLS + c] = acc / fmaxf(countsf[c], 1.0f);
}

// Fused sim GEMM + LSE + loss.
// Block = 256 threads, tile = 64 rows x 256 classes.
// Thread (tc = t&63, tr = t>>6): owns 16 rows (16*tr..) x 4 classes (4*tc..).
// Because tr == wave id, each wave holds its 16 rows' FULL class vector ->
// softmax is pure wave shuffles, no sim LDS buffer.
__global__ __launch_bounds__(256)
void k_main(const float* __restrict__ z1, const float* __restrict__ z2,
            const float* __restrict__ inv_norm, const int* __restrict__ labels,
            const float* __restrict__ meansT, double* __restrict__ loss_acc)
{
    __shared__ float z_lds[64][64];   // [d_local][row]
    const int t    = threadIdx.x;
    const int tc   = t & 63;
    const int tr   = t >> 6;
    const int row0 = blockIdx.x * 64;

    float acc[16][4] = {};

    for (int kc = 0; kc < 4; ++kc) {
        // ---- stage 64 rows x 64 dims (normalized) ----
        {
            const int r   = t >> 2;
            const int q   = t & 3;
            const int row = row0 + r;
            const float* src = (row < N_ROWS) ? (z1 + (size_t)row * D_DIM)
                                              : (z2 + (size_t)(row - N_ROWS) * D_DIM);
            const float inv = inv_norm[row];
            const float4* src4 = reinterpret_cast<const float4*>(src) + kc * 16;
            #pragma unroll
            for (int u = 0; u < 4; ++u) {
                const float4 v = src4[q * 4 + u];
                const int dl = (q * 4 + u) * 4;
                z_lds[dl + 0][r] = v.x * inv;
                z_lds[dl + 1][r] = v.y * inv;
                z_lds[dl + 2][r] = v.z * inv;
                z_lds[dl + 3][r] = v.w * inv;
            }
        }
        __syncthreads();

        const float4* mT4 =
            reinterpret_cast<const float4*>(meansT + (size_t)kc * 64 * C_CLS) + tc;
        for (int dl = 0; dl < 64; ++dl) {
            const float4 m = mT4[dl * (C_CLS / 4)];   // L1/L2-hot, coalesced
            float zv[16];
            #pragma unroll
            for (int i = 0; i < 4; ++i) {
                const float4 zz =
                    *reinterpret_cast<const float4*>(&z_lds[dl][tr * 16 + i * 4]);
                zv[i * 4 + 0] = zz.x; zv[i * 4 + 1] = zz.y;
                zv[i * 4 + 2] = zz.z; zv[i * 4 + 3] = zz.w;
            }
            #pragma unroll
            for (int i = 0; i < 16; ++i) {
                acc[i][0] = fmaf(zv[i], m.x, acc[i][0]);
                acc[i][1] = fmaf(zv[i], m.y, acc[i][1]);
                acc[i][2] = fmaf(zv[i], m.z, acc[i][2]);
                acc[i][3] = fmaf(zv[i], m.w, acc[i][3]);
            }
        }
        __syncthreads();
    }

    // ---- per-row LSE within the wave (TAU = 1) ----
    float partial = 0.0f;
    #pragma unroll 1
    for (int i = 0; i < 16; ++i) {
        const int grow = row0 + tr * 16 + i;
        const int lab  = labels[(grow < N_ROWS) ? grow : (grow - N_ROWS)];
        // sim_proto lives in lane (lab>>2), slot (lab&3): cndmask-select then bcast
        const int sl = lab & 3;
        float v = acc[i][0];
        v = (sl == 1) ? acc[i][1] : v;
        v = (sl == 2) ? acc[i][2] : v;
        v = (sl == 3) ? acc[i][3] : v;
        const float sp = __shfl(v, lab >> 2, 64);
        float s = expf(acc[i][0] - sp) + expf(acc[i][1] - sp)
                + expf(acc[i][2] - sp) + expf(acc[i][3] - sp);
        #pragma unroll
        for (int off = 32; off; off >>= 1) s += __shfl_down(s, off, 64);
        if (tc == 0) partial += sp - logf(s);
    }
    if (tc == 0) atomicAdd(loss_acc, (double)partial);
}

__global__ void k_final(const double* __restrict__ loss_acc, float* __restrict__ out)
{
    out[0] = (float)(-loss_acc[0] / (double)TWO_N);
}

extern "C" void kernel_launch(void* const* d_in, const int* in_sizes, int n_in,
                              void* d_out, int out_size, void* d_ws, size_t ws_size,
                              hipStream_t stream)
{
    const float* z1     = (const float*)d_in[0];
    const float* z2     = (const float*)d_in[1];
    const int*   labels = (const int*)d_in[2];
    float* out = (float*)d_out;
    char*  ws  = (char*)d_ws;

    int*    hist     = (int*)   (ws + WS_HIST);
    int*    cursor   = (int*)   (ws + WS_CURSOR);
    double* loss     = (double*)(ws + WS_LOSS);
    int*    offsets  = (int*)   (ws + WS_OFFSETS);
    float*  countsf  = (float*) (ws + WS_COUNTSF);
    float*  inv_norm = (float*) (ws + WS_INVNORM);
    int*    order    = (int*)   (ws + WS_ORDER);
    float*  meansT   = (float*) (ws + WS_MEANST);

    // zero hist / cursor / loss accumulator
    hipMemsetAsync(ws, 0, 4096, stream);

    hipLaunchKernelGGL(k_invnorm, dim3(TWO_N / 4), dim3(256), 0, stream, z1, z2, inv_norm);
    hipLaunchKernelGGL(k_hist,    dim3(N_ROWS / 256), dim3(256), 0, stream, labels, hist);
    hipLaunchKernelGGL(k_scan,    dim3(1), dim3(256), 0, stream, hist, offsets, countsf);
    hipLaunchKernelGGL(k_scatter, dim3(TWO_N / 256), dim3(256), 0, stream, labels, offsets, cursor, order);
    hipLaunchKernelGGL(k_means,   dim3(C_CLS), dim3(256), 0, stream, z1, z2, inv_norm, order, offsets, countsf, meansT);
    hipLaunchKernelGGL(k_main,    dim3(TWO_N / 64), dim3(256), 0, stream, z1, z2, inv_norm, labels, meansT, loss);
    hipLaunchKernelGGL(k_final,   dim3(1), dim3(1), 0, stream, loss, out);
}

// Round 2
// 371.203 us; speedup vs baseline: 1.7874x; 1.7874x over previous
//
#include <hip/hip_runtime.h>
#include <hip/hip_bf16.h>

// ProtoCLR loss, MFMA version.
// invnorm(+hist) -> scan -> scatter -> means(bf16) -> MFMA GEMM+LSE -> final.

constexpr int N_ROWS = 65536;
constexpr int D_DIM  = 256;
constexpr int C_CLS  = 256;
constexpr int TWO_N  = 2 * N_ROWS;
constexpr float EPS_NORM = 1e-12f;

typedef short  short8 __attribute__((ext_vector_type(8)));
typedef float  f32x16 __attribute__((ext_vector_type(16)));

// ---- workspace layout (bytes) ----
constexpr size_t WS_HIST    = 0;                         // int[256]
constexpr size_t WS_CURSOR  = 1024;                      // int[256]
constexpr size_t WS_OFFSETS = 2048;                      // int[257]
constexpr size_t WS_PARTIAL = 4096;                      // float[1024]
constexpr size_t WS_INVNORM = 8192;                      // float[2N]
constexpr size_t WS_ORDER   = WS_INVNORM + 4ull * TWO_N; // int[2N]
constexpr size_t WS_MEANS   = WS_ORDER + 4ull * TWO_N;   // bf16[C][D] row-major

__device__ __forceinline__ void gload_lds16(const void* g, void* l) {
    __builtin_amdgcn_global_load_lds(
        (const __attribute__((address_space(1))) void*)g,
        (__attribute__((address_space(3))) void*)l, 16, 0, 0);
}

__device__ __forceinline__ unsigned short f2bf(float x) {
    __hip_bfloat16 h = __float2bfloat16(x);
    return __builtin_bit_cast(unsigned short, h);
}

// wave per row: 1KB coalesced load, shuffle-reduce sumsq; fused label hist.
__global__ __launch_bounds__(256)
void k_invnorm(const float* __restrict__ z1, const float* __restrict__ z2,
               const int* __restrict__ labels, float* __restrict__ inv_norm,
               int* __restrict__ hist)
{
    const int w = threadIdx.x >> 6, lane = threadIdx.x & 63;
    const int wave_id = blockIdx.x * 4 + w;                 // 8192 waves
    for (int i = 0; i < 16; ++i) {
        const int row = wave_id + 8192 * i;
        const float* src = (row < N_ROWS) ? z1 + (size_t)row * D_DIM
                                          : z2 + (size_t)(row - N_ROWS) * D_DIM;
        const float4 v = reinterpret_cast<const float4*>(src)[lane];
        float s = v.x * v.x + v.y * v.y + v.z * v.z + v.w * v.w;
        #pragma unroll
        for (int off = 32; off; off >>= 1) s += __shfl_down(s, off, 64);
        if (lane == 0) {
            inv_norm[row] = 1.0f / fmaxf(sqrtf(s), EPS_NORM);
            if (row < N_ROWS) atomicAdd(&hist[labels[row]], 1);
        }
    }
}

__global__ __launch_bounds__(256)
void k_scan(const int* __restrict__ hist, int* __restrict__ offsets)
{
    __shared__ int tmp[C_CLS];
    const int t = threadIdx.x;
    tmp[t] = hist[t] * 2;              // both views share labels
    __syncthreads();
    if (t == 0) {
        int acc = 0;
        for (int c = 0; c < C_CLS; ++c) { offsets[c] = acc; acc += tmp[c]; }
        offsets[C_CLS] = acc;
    }
}

__global__ __launch_bounds__(256)
void k_scatter(const int* __restrict__ labels, const int* __restrict__ offsets,
               int* __restrict__ cursor, int* __restrict__ order)
{
    const int i = blockIdx.x * 256 + threadIdx.x;
    if (i < TWO_N) {
        const int lab = labels[(i < N_ROWS) ? i : (i - N_ROWS)];
        const int pos = offsets[lab] + atomicAdd(&cursor[lab], 1);
        order[pos] = i;
    }
}

// block per class; wave per row (1KB coalesced), f32 accumulate, bf16 means out.
__global__ __launch_bounds__(256)
void k_means(const float* __restrict__ z1, const float* __restrict__ z2,
             const float* __restrict__ inv_norm, const int* __restrict__ order,
             const int* __restrict__ offsets, __hip_bfloat16* __restrict__ means)
{
    __shared__ float red[4][D_DIM];
    const int c = blockIdx.x;
    const int lane = threadIdx.x & 63, w = threadIdx.x >> 6;
    const int s = offsets[c], e = offsets[c + 1];
    float ax = 0.f, ay = 0.f, az = 0.f, aw = 0.f;
    int idx = s + w;
    for (; idx + 4 < e; idx += 8) {          // 2 rows in flight per wave
        const int r1 = order[idx], r2 = order[idx + 4];
        const float* s1 = (r1 < N_ROWS) ? z1 + (size_t)r1 * D_DIM
                                        : z2 + (size_t)(r1 - N_ROWS) * D_DIM;
        const float* s2 = (r2 < N_ROWS) ? z1 + (size_t)r2 * D_DIM
                                        : z2 + (size_t)(r2 - N_ROWS) * D_DIM;
        const float4 v1 = reinterpret_cast<const float4*>(s1)[lane];
        const float4 v2 = reinterpret_cast<const float4*>(s2)[lane];
        const float i1 = inv_norm[r1], i2 = inv_norm[r2];
        ax += v1.x * i1 + v2.x * i2;  ay += v1.y * i1 + v2.y * i2;
        az += v1.z * i1 + v2.z * i2;  aw += v1.w * i1 + v2.w * i2;
    }
    if (idx < e) {
        const int r1 = order[idx];
        const float* s1 = (r1 < N_ROWS) ? z1 + (size_t)r1 * D_DIM
                                        : z2 + (size_t)(r1 - N_ROWS) * D_DIM;
        const float4 v1 = reinterpret_cast<const float4*>(s1)[lane];
        const float i1 = inv_norm[r1];
        ax += v1.x * i1; ay += v1.y * i1; az += v1.z * i1; aw += v1.w * i1;
    }
    red[w][4 * lane + 0] = ax; red[w][4 * lane + 1] = ay;
    red[w][4 * lane + 2] = az; red[w][4 * lane + 3] = aw;
    __syncthreads();
    if (w == 0) {
        const float invc = 1.0f / fmaxf((float)(e - s), 1.0f);
        ushort4 o;
        o.x = f2bf((red[0][4*lane+0] + red[1][4*lane+0] + red[2][4*lane+0] + red[3][4*lane+0]) * invc);
        o.y = f2bf((red[0][4*lane+1] + red[1][4*lane+1] + red[2][4*lane+1] + red[3][4*lane+1]) * invc);
        o.z = f2bf((red[0][4*lane+2] + red[1][4*lane+2] + red[2][4*lane+2] + red[3][4*lane+2]) * invc);
        o.w = f2bf((red[0][4*lane+3] + red[1][4*lane+3] + red[2][4*lane+3] + red[3][4*lane+3]) * invc);
        *reinterpret_cast<ushort4*>(means + (size_t)c * D_DIM + 4 * lane) = o;
    }
}

// Fused MFMA GEMM (sim = zn @ means^T) + LSE + loss partial.
// Block: 256 thr (4 waves), tile 128 rows x 256 cls, BK=64.
// Wave (wr=w>>1, wc=w&1): 64 rows x 128 cls = 2 rtiles x 4 ntiles of 32x32.
// LDS: A dbuf 2x16KB @0, B 32KB @32768. XOR swizzle byte^=((row&7)<<4).
__global__ __launch_bounds__(256, 2)
void k_main(const float* __restrict__ z1, const float* __restrict__ z2,
            const float* __restrict__ inv_norm, const int* __restrict__ labels,
            const __hip_bfloat16* __restrict__ means, float* __restrict__ partials)
{
    __shared__ char smem[65536];
    const int t    = threadIdx.x;
    const int lane = t & 63;
    const int w    = t >> 6;
    const int wr   = w >> 1, wc = w & 1;
    const int row0 = blockIdx.x * 128;

    // A staging assignment: 2 threads/row, 8 float4 (=32 elems) each
    const int a_row   = t >> 1;
    const int a_cbase = (t & 1) * 64;          // byte col base within 128B row
    const int a_swz   = (a_row & 7) << 4;
    const int grow_a  = row0 + a_row;
    const float* zsrc = (grow_a < N_ROWS) ? z1 + (size_t)grow_a * D_DIM
                                          : z2 + (size_t)(grow_a - N_ROWS) * D_DIM;
    const float inv_a = inv_norm[grow_a];

    // fragment read bases
    const int l31 = lane & 31;
    const int g16 = (lane >> 5) * 16;
    const int swz = (lane & 7) << 4;

    f32x16 acc[2][4] = {};

    // ---------------- prologue ----------------
    {   // stage B chunk 0
        #pragma unroll
        for (int i = 0; i < 8; ++i) {
            const int chunk = w * 8 + i;
            const int c  = chunk * 8 + (lane >> 3);
            const int cb = ((lane & 7) ^ (lane >> 3)) << 4;
            gload_lds16((const char*)means + (size_t)c * 512 + cb,
                        smem + 32768 + chunk * 1024);
        }
        float4 ld[8];
        #pragma unroll
        for (int q = 0; q < 8; ++q)
            ld[q] = *reinterpret_cast<const float4*>(zsrc + (a_cbase >> 1) + q * 4);
        #pragma unroll
        for (int q = 0; q < 8; ++q) {
            ushort4 o;
            o.x = f2bf(ld[q].x * inv_a); o.y = f2bf(ld[q].y * inv_a);
            o.z = f2bf(ld[q].z * inv_a); o.w = f2bf(ld[q].w * inv_a);
            *reinterpret_cast<ushort4*>(smem + a_row * 128 + ((a_cbase + q * 8) ^ a_swz)) = o;
        }
    }
    __syncthreads();

    // ---------------- K loop (4 iters of BK=64) ----------------
    for (int kt = 0; kt < 4; ++kt) {
        const int abuf = (kt & 1) * 16384;
        float4 nxt[8];
        if (kt < 3) {
            #pragma unroll
            for (int q = 0; q < 8; ++q)
                nxt[q] = *reinterpret_cast<const float4*>(
                    zsrc + (kt + 1) * 64 + (a_cbase >> 1) + q * 4);
        }
        // compute: 4 ksteps of 16
        #pragma unroll
        for (int ks = 0; ks < 4; ++ks) {
            const int cb  = (ks * 32 + g16);
            const short8 a0 = *reinterpret_cast<const short8*>(
                smem + abuf + (wr * 64 + l31) * 128 + (cb ^ swz));
            const short8 a1 = *reinterpret_cast<const short8*>(
                smem + abuf + (wr * 64 + 32 + l31) * 128 + (cb ^ swz));
            short8 b[4];
            #pragma unroll
            for (int n = 0; n < 4; ++n)
                b[n] = *reinterpret_cast<const short8*>(
                    smem + 32768 + (wc * 128 + n * 32 + l31) * 128 + (cb ^ swz));
            #pragma unroll
            for (int n = 0; n < 4; ++n) {
                acc[0][n] = __builtin_amdgcn_mfma_f32_32x32x16_bf16(a0, b[n], acc[0][n], 0, 0, 0);
                acc[1][n] = __builtin_amdgcn_mfma_f32_32x32x16_bf16(a1, b[n], acc[1][n], 0, 0, 0);
            }
        }
        if (kt < 3) {
            #pragma unroll
            for (int q = 0; q < 8; ++q) {
                ushort4 o;
                o.x = f2bf(nxt[q].x * inv_a); o.y = f2bf(nxt[q].y * inv_a);
                o.z = f2bf(nxt[q].z * inv_a); o.w = f2bf(nxt[q].w * inv_a);
                *reinterpret_cast<ushort4*>(
                    smem + ((kt + 1) & 1) * 16384 + a_row * 128 + ((a_cbase + q * 8) ^ a_swz)) = o;
            }
        }
        __syncthreads();
        if (kt < 3) {
            #pragma unroll
            for (int i = 0; i < 8; ++i) {
                const int chunk = w * 8 + i;
                const int c  = chunk * 8 + (lane >> 3);
                const int cb = ((lane & 7) ^ (lane >> 3)) << 4;
                gload_lds16((const char*)means + (size_t)c * 512 + (kt + 1) * 128 + cb,
                            smem + 32768 + chunk * 1024);
            }
            __syncthreads();
        }
    }

    // ---------------- epilogue: LSE over 256 classes, 2 rounds of 64 rows ----
    float* simf = reinterpret_cast<float*>(smem);   // [64][256] f32 = 64KB
    float partial = 0.0f;
    for (int r = 0; r < 2; ++r) {
        if (wr == r) {
            #pragma unroll
            for (int rt = 0; rt < 2; ++rt)
                #pragma unroll
                for (int n = 0; n < 4; ++n)
                    #pragma unroll
                    for (int q = 0; q < 16; ++q) {
                        const int row64 = rt * 32 + (q & 3) + 8 * (q >> 2) + 4 * (lane >> 5);
                        const int col   = wc * 128 + n * 32 + l31;
                        simf[row64 * 256 + col] = acc[rt][n][q];
                    }
        }
        __syncthreads();
        #pragma unroll 1
        for (int i = 0; i < 16; ++i) {
            const int rl   = w * 16 + i;
            const int grow = row0 + r * 64 + rl;
            float s = __expf(simf[rl * 256 + lane])       + __expf(simf[rl * 256 + 64 + lane])
                    + __expf(simf[rl * 256 + 128 + lane]) + __expf(simf[rl * 256 + 192 + lane]);
            #pragma unroll
            for (int off = 32; off; off >>= 1) s += __shfl_down(s, off, 64);
            const int lab = labels[(grow < N_ROWS) ? grow : grow - N_ROWS];
            const float sp = simf[rl * 256 + lab];
            if (lane == 0) partial += 2.0f * sp - logf(s);
        }
        __syncthreads();
    }
    if (lane == 0) simf[w] = partial;
    __syncthreads();
    if (t == 0) partials[blockIdx.x] = simf[0] + simf[1] + simf[2] + simf[3];
}

__global__ __launch_bounds__(256)
void k_final(const float* __restrict__ partials, float* __restrict__ out)
{
    __shared__ float red[4];
    const int t = threadIdx.x, lane = t & 63, w = t >> 6;
    float s = partials[t] + partials[t + 256] + partials[t + 512] + partials[t + 768];
    #pragma unroll
    for (int off = 32; off; off >>= 1) s += __shfl_down(s, off, 64);
    if (lane == 0) red[w] = s;
    __syncthreads();
    if (t == 0) out[0] = -(red[0] + red[1] + red[2] + red[3]) / (float)TWO_N;
}

extern "C" void kernel_launch(void* const* d_in, const int* in_sizes, int n_in,
                              void* d_out, int out_size, void* d_ws, size_t ws_size,
                              hipStream_t stream)
{
    const float* z1     = (const float*)d_in[0];
    const float* z2     = (const float*)d_in[1];
    const int*   labels = (const int*)d_in[2];
    float* out = (float*)d_out;
    char*  ws  = (char*)d_ws;

    int*   hist     = (int*)  (ws + WS_HIST);
    int*   cursor   = (int*)  (ws + WS_CURSOR);
    int*   offsets  = (int*)  (ws + WS_OFFSETS);
    float* partials = (float*)(ws + WS_PARTIAL);
    float* inv_norm = (float*)(ws + WS_INVNORM);
    int*   order    = (int*)  (ws + WS_ORDER);
    __hip_bfloat16* means = (__hip_bfloat16*)(ws + WS_MEANS);

    hipMemsetAsync(ws, 0, 2048, stream);   // hist + cursor

    hipLaunchKernelGGL(k_invnorm, dim3(2048), dim3(256), 0, stream, z1, z2, labels, inv_norm, hist);
    hipLaunchKernelGGL(k_scan,    dim3(1), dim3(256), 0, stream, hist, offsets);
    hipLaunchKernelGGL(k_scatter, dim3(TWO_N / 256), dim3(256), 0, stream, labels, offsets, cursor, order);
    hipLaunchKernelGGL(k_means,   dim3(C_CLS), dim3(256), 0, stream, z1, z2, inv_norm, order, offsets, means);
    hipLaunchKernelGGL(k_main,    dim3(TWO_N / 128), dim3(256), 0, stream, z1, z2, inv_norm, labels, means, partials);
    hipLaunchKernelGGL(k_final,   dim3(1), dim3(256), 0, stream, partials, out);
}

// Round 3
// 236.684 us; speedup vs baseline: 2.8033x; 1.5683x over previous
//
#include <hip/hip_runtime.h>
#include <hip/hip_bf16.h>

// ProtoCLR loss on MI355X.
// k_norm (inv-norms) -> k_scatter (bucketed counting sort, LDS-privatized)
// -> k_means (segmented partial sums) -> k_means2 (reduce+bf16 means)
// -> k_main (MFMA GEMM + fused LSE) -> k_final.

constexpr int N_ROWS = 65536;
constexpr int D_DIM  = 256;
constexpr int C_CLS  = 256;
constexpr int TWO_N  = 2 * N_ROWS;
constexpr int BUCKET = 1024;            // per-class capacity (mean 512, +22 sigma)
constexpr float EPS_NORM = 1e-12f;

typedef short          short8   __attribute__((ext_vector_type(8)));
typedef float          f32x16   __attribute__((ext_vector_type(16)));
typedef unsigned short ushort8v __attribute__((ext_vector_type(8)));

// ---- workspace layout (bytes) ----
constexpr size_t WS_CURSOR = 0;                               // int[256] (zeroed)
constexpr size_t WS_LOSSP  = 4096;                            // float[1024]
constexpr size_t WS_INVN   = 8192;                            // float[2N] (1MB)
constexpr size_t WS_ORDER  = WS_INVN + 4ull * TWO_N;          // int[C*BUCKET] (1MB)
constexpr size_t WS_MEANP  = WS_ORDER + 4ull * C_CLS * BUCKET;// float[4*C*D] (1MB)
constexpr size_t WS_MEANS  = WS_MEANP + 16ull * C_CLS * D_DIM;// bf16[C*D] (128KB)

__device__ __forceinline__ void gload_lds16(const void* g, void* l) {
    __builtin_amdgcn_global_load_lds(
        (const __attribute__((address_space(1))) void*)g,
        (__attribute__((address_space(3))) void*)l, 16, 0, 0);
}

__device__ __forceinline__ unsigned short f2bf(float x) {
    __hip_bfloat16 h = __float2bfloat16(x);
    return __builtin_bit_cast(unsigned short, h);
}

// ---- 1. row inverse norms (no atomics in hot loop, ILP-4) ----
__global__ __launch_bounds__(256)
void k_norm(const float* __restrict__ z1, const float* __restrict__ z2,
            float* __restrict__ inv_norm)
{
    const int w = threadIdx.x >> 6, lane = threadIdx.x & 63;
    const int wave = blockIdx.x * 4 + w;              // 8192 waves
    #pragma unroll 1
    for (int b = 0; b < 4; ++b) {
        int r[4]; float4 v[4]; float s[4];
        #pragma unroll
        for (int j = 0; j < 4; ++j) {
            r[j] = wave + 8192 * (b * 4 + j);
            const float* src = (r[j] < N_ROWS) ? z1 + (size_t)r[j] * D_DIM
                                               : z2 + (size_t)(r[j] - N_ROWS) * D_DIM;
            v[j] = reinterpret_cast<const float4*>(src)[lane];
        }
        #pragma unroll
        for (int j = 0; j < 4; ++j)
            s[j] = v[j].x * v[j].x + v[j].y * v[j].y + v[j].z * v[j].z + v[j].w * v[j].w;
        #pragma unroll
        for (int off = 1; off < 64; off <<= 1) {
            #pragma unroll
            for (int j = 0; j < 4; ++j) s[j] += __shfl_xor(s[j], off, 64);
        }
        if (lane == 0) {
            #pragma unroll
            for (int j = 0; j < 4; ++j)
                inv_norm[r[j]] = 1.0f / fmaxf(sqrtf(s[j]), EPS_NORM);
        }
    }
}

// ---- 2. bucketed counting-sort scatter (LDS-privatized cursors) ----
__global__ __launch_bounds__(256)
void k_scatter(const int* __restrict__ labels, int* __restrict__ cursor,
               int* __restrict__ order)
{
    __shared__ int lcur[C_CLS];
    __shared__ int lbase[C_CLS];
    const int t = threadIdx.x;
    lcur[t] = 0;
    __syncthreads();
    const int i0 = blockIdx.x * 2048;                 // 64 blocks x 2048 rows
    int lab[8], lpos[8];
    #pragma unroll
    for (int u = 0; u < 8; ++u) {
        const int i = i0 + u * 256 + t;
        lab[u] = labels[(i < N_ROWS) ? i : (i - N_ROWS)];
        lpos[u] = atomicAdd(&lcur[lab[u]], 1);
    }
    __syncthreads();
    if (lcur[t] > 0) lbase[t] = atomicAdd(&cursor[t], lcur[t]);
    __syncthreads();
    #pragma unroll
    for (int u = 0; u < 8; ++u)
        order[lab[u] * BUCKET + lbase[lab[u]] + lpos[u]] = i0 + u * 256 + t;
}

// ---- 3. per-(class, segment) partial sums, ILP-4 gathers ----
__global__ __launch_bounds__(256)
void k_means(const float* __restrict__ z1, const float* __restrict__ z2,
             const float* __restrict__ inv_norm, const int* __restrict__ cursor,
             const int* __restrict__ order, float* __restrict__ meanp)
{
    __shared__ float4 red4[4][64];
    const int c = blockIdx.x, sgt = blockIdx.y;
    const int lane = threadIdx.x & 63, w = threadIdx.x >> 6;
    const int cnt = cursor[c];
    const int chunk = (cnt + 3) >> 2;
    const int beg = sgt * chunk;
    const int end = min(beg + chunk, cnt);
    const int* ord = order + c * BUCKET;
    float4 acc = {0.f, 0.f, 0.f, 0.f};
    int idx = beg + w;
    for (; idx + 12 < end; idx += 16) {
        int rr[4]; float4 v[4]; float iv[4];
        #pragma unroll
        for (int u = 0; u < 4; ++u) rr[u] = ord[idx + 4 * u];
        #pragma unroll
        for (int u = 0; u < 4; ++u) {
            const float* src = (rr[u] < N_ROWS) ? z1 + (size_t)rr[u] * D_DIM
                                                : z2 + (size_t)(rr[u] - N_ROWS) * D_DIM;
            v[u] = reinterpret_cast<const float4*>(src)[lane];
            iv[u] = inv_norm[rr[u]];
        }
        #pragma unroll
        for (int u = 0; u < 4; ++u) {
            acc.x = fmaf(v[u].x, iv[u], acc.x);
            acc.y = fmaf(v[u].y, iv[u], acc.y);
            acc.z = fmaf(v[u].z, iv[u], acc.z);
            acc.w = fmaf(v[u].w, iv[u], acc.w);
        }
    }
    for (; idx < end; idx += 4) {
        const int r1 = ord[idx];
        const float* src = (r1 < N_ROWS) ? z1 + (size_t)r1 * D_DIM
                                         : z2 + (size_t)(r1 - N_ROWS) * D_DIM;
        const float4 v = reinterpret_cast<const float4*>(src)[lane];
        const float iv = inv_norm[r1];
        acc.x = fmaf(v.x, iv, acc.x); acc.y = fmaf(v.y, iv, acc.y);
        acc.z = fmaf(v.z, iv, acc.z); acc.w = fmaf(v.w, iv, acc.w);
    }
    red4[w][lane] = acc;
    __syncthreads();
    if (w == 0) {
        const float4 a0 = red4[0][lane], a1 = red4[1][lane];
        const float4 a2 = red4[2][lane], a3 = red4[3][lane];
        float4 o;
        o.x = a0.x + a1.x + a2.x + a3.x;  o.y = a0.y + a1.y + a2.y + a3.y;
        o.z = a0.z + a1.z + a2.z + a3.z;  o.w = a0.w + a1.w + a2.w + a3.w;
        *reinterpret_cast<float4*>(meanp + ((size_t)c * 4 + sgt) * D_DIM + 4 * lane) = o;
    }
}

// ---- 4. reduce 4 segments -> bf16 means ----
__global__ __launch_bounds__(256)
void k_means2(const float* __restrict__ meanp, const int* __restrict__ cursor,
              __hip_bfloat16* __restrict__ means)
{
    const int tid = blockIdx.x * 256 + threadIdx.x;   // 64 blocks -> 16384
    const int c = tid >> 6, l = tid & 63;
    const float invc = 1.0f / fmaxf((float)cursor[c], 1.0f);
    const float4 s0 = *reinterpret_cast<const float4*>(meanp + ((size_t)c * 4 + 0) * D_DIM + 4 * l);
    const float4 s1 = *reinterpret_cast<const float4*>(meanp + ((size_t)c * 4 + 1) * D_DIM + 4 * l);
    const float4 s2 = *reinterpret_cast<const float4*>(meanp + ((size_t)c * 4 + 2) * D_DIM + 4 * l);
    const float4 s3 = *reinterpret_cast<const float4*>(meanp + ((size_t)c * 4 + 3) * D_DIM + 4 * l);
    ushort4 o;
    o.x = f2bf((s0.x + s1.x + s2.x + s3.x) * invc);
    o.y = f2bf((s0.y + s1.y + s2.y + s3.y) * invc);
    o.z = f2bf((s0.z + s1.z + s2.z + s3.z) * invc);
    o.w = f2bf((s0.w + s1.w + s2.w + s3.w) * invc);
    *reinterpret_cast<ushort4*>(means + (size_t)c * D_DIM + 4 * l) = o;
}

// ---- 5. MFMA GEMM (sim = zn @ means^T) + fused LSE ----
// 1024 blocks x 256 thr (4 waves). Tile 128 rows x 256 cls, BK=32, 8 kts.
// LDS 64KB: A dbuf 2x8KB @0, B dbuf 2x16KB @16K; epilogue reuses all 64KB.
// XOR key ((row&3)^((row>>3)&3))<<4 -> conflict-free stride-64B frag reads.
__global__ __launch_bounds__(256, 2)
void k_main(const float* __restrict__ z1, const float* __restrict__ z2,
            const float* __restrict__ inv_norm, const int* __restrict__ labels,
            const __hip_bfloat16* __restrict__ means, float* __restrict__ lossp)
{
    __shared__ char smem[65536];
    const int t    = threadIdx.x;
    const int lane = t & 63;
    const int w    = t >> 6;
    const int wr   = w >> 1, wc = w & 1;
    const int l31  = lane & 31;
    const int g16  = (lane >> 5) << 4;
    const int row0 = blockIdx.x * 128;

    // A staging: thread -> (row = t>>1, half = t&1), 16 dims (64B f32) per kt
    const int a_row  = t >> 1;
    const int a_half = t & 1;
    const int grow   = row0 + a_row;
    const float* zsrc = (grow < N_ROWS) ? z1 + (size_t)grow * D_DIM
                                        : z2 + (size_t)(grow - N_ROWS) * D_DIM;
    const float inv_a = inv_norm[grow];
    const int  a_key  = (((a_row & 3) ^ ((a_row >> 3) & 3)) << 4);
    char* const aw0 = smem + a_row * 64 + ((a_half * 32 + 0)  ^ a_key);
    char* const aw1 = smem + a_row * 64 + ((a_half * 32 + 16) ^ a_key);

    const int rkey = (((l31 & 3) ^ ((l31 >> 3) & 3)) << 4);
    f32x16 acc[2][4] = {};
    float4 pre[4];

    auto A_LOAD = [&](int kt) {
        const float4* s = reinterpret_cast<const float4*>(zsrc + kt * 32 + a_half * 16);
        pre[0] = s[0]; pre[1] = s[1]; pre[2] = s[2]; pre[3] = s[3];
    };
    auto A_WRITE = [&](int buf) {
        ushort8v o1, o2;
        o1[0] = f2bf(pre[0].x * inv_a); o1[1] = f2bf(pre[0].y * inv_a);
        o1[2] = f2bf(pre[0].z * inv_a); o1[3] = f2bf(pre[0].w * inv_a);
        o1[4] = f2bf(pre[1].x * inv_a); o1[5] = f2bf(pre[1].y * inv_a);
        o1[6] = f2bf(pre[1].z * inv_a); o1[7] = f2bf(pre[1].w * inv_a);
        o2[0] = f2bf(pre[2].x * inv_a); o2[1] = f2bf(pre[2].y * inv_a);
        o2[2] = f2bf(pre[2].z * inv_a); o2[3] = f2bf(pre[2].w * inv_a);
        o2[4] = f2bf(pre[3].x * inv_a); o2[5] = f2bf(pre[3].y * inv_a);
        o2[6] = f2bf(pre[3].z * inv_a); o2[7] = f2bf(pre[3].w * inv_a);
        *reinterpret_cast<ushort8v*>(aw0 + buf * 8192) = o1;
        *reinterpret_cast<ushort8v*>(aw1 + buf * 8192) = o2;
    };
    auto B_STAGE = [&](int kt, int buf) {
        #pragma unroll
        for (int q = 0; q < 4; ++q) {
            const int g   = q * 256 + t;
            const int c   = g >> 2;
            const int cb  = (g & 3) << 4;
            const int key = (((c & 3) ^ ((c >> 3) & 3)) << 4);
            gload_lds16((const char*)means + (size_t)c * 512 + kt * 64 + (cb ^ key),
                        smem + 16384 + buf * 16384 + q * 4096 + w * 1024);
        }
    };
    auto COMPUTE = [&](int buf) {
        const char* ab = smem + buf * 8192;
        const char* bb = smem + 16384 + buf * 16384;
        #pragma unroll
        for (int ks = 0; ks < 2; ++ks) {
            const int cb = (ks * 32 + g16) ^ rkey;
            const short8 a0 = *reinterpret_cast<const short8*>(ab + (wr * 64 + l31) * 64 + cb);
            const short8 a1 = *reinterpret_cast<const short8*>(ab + (wr * 64 + 32 + l31) * 64 + cb);
            short8 bfr[4];
            #pragma unroll
            for (int n = 0; n < 4; ++n)
                bfr[n] = *reinterpret_cast<const short8*>(bb + (wc * 128 + n * 32 + l31) * 64 + cb);
            #pragma unroll
            for (int n = 0; n < 4; ++n) {
                acc[0][n] = __builtin_amdgcn_mfma_f32_32x32x16_bf16(a0, bfr[n], acc[0][n], 0, 0, 0);
                acc[1][n] = __builtin_amdgcn_mfma_f32_32x32x16_bf16(a1, bfr[n], acc[1][n], 0, 0, 0);
            }
        }
    };

    // prologue: fill buf0
    B_STAGE(0, 0);
    A_LOAD(0);
    A_WRITE(0);
    // main loop: 1 barrier per kt, next-tile loads in flight under compute
    #pragma unroll
    for (int kt = 0; kt < 8; ++kt) {
        __syncthreads();                       // drains vmcnt+lgkm: buf[kt&1] ready
        if (kt < 7) { B_STAGE(kt + 1, (kt + 1) & 1); A_LOAD(kt + 1); }
        COMPUTE(kt & 1);
        if (kt < 7) A_WRITE((kt + 1) & 1);
    }
    __syncthreads();

    // epilogue: LSE over 256 classes, 2 rounds of 64 rows (smem reused as sim)
    float* simf = reinterpret_cast<float*>(smem);
    float partial = 0.0f;
    for (int rhalf = 0; rhalf < 2; ++rhalf) {
        if (wr == rhalf) {
            #pragma unroll
            for (int rt = 0; rt < 2; ++rt)
                #pragma unroll
                for (int n = 0; n < 4; ++n)
                    #pragma unroll
                    for (int q = 0; q < 16; ++q) {
                        const int row64 = rt * 32 + (q & 3) + 8 * (q >> 2) + 4 * (lane >> 5);
                        const int col   = wc * 128 + n * 32 + l31;
                        simf[row64 * 256 + col] = acc[rt][n][q];
                    }
        }
        __syncthreads();
        #pragma unroll 1
        for (int i = 0; i < 16; ++i) {
            const int rl    = w * 16 + i;
            const int growr = row0 + rhalf * 64 + rl;
            float s = __expf(simf[rl * 256 + lane])       + __expf(simf[rl * 256 + 64 + lane])
                    + __expf(simf[rl * 256 + 128 + lane]) + __expf(simf[rl * 256 + 192 + lane]);
            #pragma unroll
            for (int off = 32; off; off >>= 1) s += __shfl_down(s, off, 64);
            const int lab = labels[(growr < N_ROWS) ? growr : growr - N_ROWS];
            const float sp = simf[rl * 256 + lab];
            if (lane == 0) partial += 2.0f * sp - logf(s);
        }
        __syncthreads();
    }
    if (lane == 0) simf[w] = partial;
    __syncthreads();
    if (t == 0) lossp[blockIdx.x] = simf[0] + simf[1] + simf[2] + simf[3];
}

// ---- 6. final reduce ----
__global__ __launch_bounds__(256)
void k_final(const float* __restrict__ lossp, float* __restrict__ out)
{
    __shared__ float red[4];
    const int t = threadIdx.x, lane = t & 63, w = t >> 6;
    float s = lossp[t] + lossp[t + 256] + lossp[t + 512] + lossp[t + 768];
    #pragma unroll
    for (int off = 32; off; off >>= 1) s += __shfl_down(s, off, 64);
    if (lane == 0) red[w] = s;
    __syncthreads();
    if (t == 0) out[0] = -(red[0] + red[1] + red[2] + red[3]) / (float)TWO_N;
}

extern "C" void kernel_launch(void* const* d_in, const int* in_sizes, int n_in,
                              void* d_out, int out_size, void* d_ws, size_t ws_size,
                              hipStream_t stream)
{
    const float* z1     = (const float*)d_in[0];
    const float* z2     = (const float*)d_in[1];
    const int*   labels = (const int*)d_in[2];
    float* out = (float*)d_out;
    char*  ws  = (char*)d_ws;

    int*   cursor   = (int*)  (ws + WS_CURSOR);
    float* lossp    = (float*)(ws + WS_LOSSP);
    float* inv_norm = (float*)(ws + WS_INVN);
    int*   order    = (int*)  (ws + WS_ORDER);
    float* meanp    = (float*)(ws + WS_MEANP);
    __hip_bfloat16* means = (__hip_bfloat16*)(ws + WS_MEANS);

    hipMemsetAsync(ws, 0, 4096, stream);   // cursors

    hipLaunchKernelGGL(k_norm,    dim3(2048), dim3(256), 0, stream, z1, z2, inv_norm);
    hipLaunchKernelGGL(k_scatter, dim3(64),   dim3(256), 0, stream, labels, cursor, order);
    hipLaunchKernelGGL(k_means,   dim3(256, 4), dim3(256), 0, stream, z1, z2, inv_norm, cursor, order, meanp);
    hipLaunchKernelGGL(k_means2,  dim3(64),   dim3(256), 0, stream, meanp, cursor, means);
    hipLaunchKernelGGL(k_main,    dim3(TWO_N / 128), dim3(256), 0, stream, z1, z2, inv_norm, labels, means, lossp);
    hipLaunchKernelGGL(k_final,   dim3(1),    dim3(256), 0, stream, lossp, out);
}

// Round 4
// 222.603 us; speedup vs baseline: 2.9806x; 1.0633x over previous
//
#include <hip/hip_runtime.h>
#include <hip/hip_bf16.h>

// ProtoCLR loss on MI355X.
// Cached path (needs ~66MB ws): k_norm (f32 z -> normalized bf16 znb)
//   -> k_scatter -> k_means (bf16 gather) -> k_means2 -> k_main (MFMA +
//   in-register LSE + atomic loss).
// Fallback path (ws too small): round-3 kernels verbatim.

constexpr int N_ROWS = 65536;
constexpr int D_DIM  = 256;
constexpr int C_CLS  = 256;
constexpr int TWO_N  = 2 * N_ROWS;
constexpr int BUCKET = 1024;
constexpr float EPS_NORM = 1e-12f;

typedef short          short8   __attribute__((ext_vector_type(8)));
typedef float          f32x16   __attribute__((ext_vector_type(16)));
typedef unsigned short ushort8v __attribute__((ext_vector_type(8)));

// ---- cached-path workspace layout (bytes) ----
constexpr size_t CW_CURSOR = 0;                                  // int[256]
constexpr size_t CW_MEANP  = 4096;                               // f32[2][256][256] 512KB
constexpr size_t CW_MEANS  = CW_MEANP + 524288;                  // bf16[256][256] 128KB
constexpr size_t CW_ORDER  = CW_MEANS + 131072;                  // int[256*1024] 1MB
constexpr size_t CW_ZNB    = CW_ORDER + 1048576;                 // bf16[2N][256] 64MB
constexpr size_t CW_NEED   = CW_ZNB + 2ull * TWO_N * D_DIM;      // ~65.6MB

// ---- fallback workspace layout (round 3, proven) ----
constexpr size_t FW_CURSOR = 0;
constexpr size_t FW_LOSSP  = 4096;
constexpr size_t FW_INVN   = 8192;
constexpr size_t FW_ORDER  = FW_INVN + 4ull * TWO_N;
constexpr size_t FW_MEANP  = FW_ORDER + 4ull * C_CLS * BUCKET;
constexpr size_t FW_MEANS  = FW_MEANP + 16ull * C_CLS * D_DIM;

__device__ __forceinline__ void gload_lds16(const void* g, void* l) {
    __builtin_amdgcn_global_load_lds(
        (const __attribute__((address_space(1))) void*)g,
        (__attribute__((address_space(3))) void*)l, 16, 0, 0);
}
__device__ __forceinline__ unsigned short f2bf(float x) {
    __hip_bfloat16 h = __float2bfloat16(x);
    return __builtin_bit_cast(unsigned short, h);
}
__device__ __forceinline__ float bf2f(unsigned short u) {
    return __uint_as_float(((unsigned int)u) << 16);
}

// ================= shared: bucketed counting-sort scatter =================
__global__ __launch_bounds__(256)
void k_scatter(const int* __restrict__ labels, int* __restrict__ cursor,
               int* __restrict__ order)
{
    __shared__ int lcur[C_CLS];
    __shared__ int lbase[C_CLS];
    const int t = threadIdx.x;
    lcur[t] = 0;
    __syncthreads();
    const int i0 = blockIdx.x * 2048;
    int lab[8], lpos[8];
    #pragma unroll
    for (int u = 0; u < 8; ++u) {
        const int i = i0 + u * 256 + t;
        lab[u] = labels[(i < N_ROWS) ? i : (i - N_ROWS)];
        lpos[u] = atomicAdd(&lcur[lab[u]], 1);
    }
    __syncthreads();
    if (lcur[t] > 0) lbase[t] = atomicAdd(&cursor[t], lcur[t]);
    __syncthreads();
    #pragma unroll
    for (int u = 0; u < 8; ++u)
        order[lab[u] * BUCKET + lbase[lab[u]] + lpos[u]] = i0 + u * 256 + t;
}

// ========================== CACHED PATH ==========================

// z (f32) -> normalized bf16 znb. wave per row, ILP-2.
__global__ __launch_bounds__(256)
void k_norm(const float* __restrict__ z1, const float* __restrict__ z2,
            __hip_bfloat16* __restrict__ znb)
{
    const int w = threadIdx.x >> 6, lane = threadIdx.x & 63;
    const int wave = blockIdx.x * 4 + w;              // 8192 waves x 16 rows
    #pragma unroll 1
    for (int b = 0; b < 8; ++b) {
        const int r0 = wave + 8192 * (2 * b);
        const int r1 = wave + 8192 * (2 * b + 1);
        const float* s0p = (r0 < N_ROWS) ? z1 + (size_t)r0 * D_DIM
                                         : z2 + (size_t)(r0 - N_ROWS) * D_DIM;
        const float* s1p = (r1 < N_ROWS) ? z1 + (size_t)r1 * D_DIM
                                         : z2 + (size_t)(r1 - N_ROWS) * D_DIM;
        const float4 v0 = reinterpret_cast<const float4*>(s0p)[lane];
        const float4 v1 = reinterpret_cast<const float4*>(s1p)[lane];
        float s0 = v0.x * v0.x + v0.y * v0.y + v0.z * v0.z + v0.w * v0.w;
        float s1 = v1.x * v1.x + v1.y * v1.y + v1.z * v1.z + v1.w * v1.w;
        #pragma unroll
        for (int off = 1; off < 64; off <<= 1) {
            s0 += __shfl_xor(s0, off, 64);
            s1 += __shfl_xor(s1, off, 64);
        }
        const float i0 = 1.0f / fmaxf(sqrtf(s0), EPS_NORM);
        const float i1 = 1.0f / fmaxf(sqrtf(s1), EPS_NORM);
        ushort4 o0, o1;
        o0.x = f2bf(v0.x * i0); o0.y = f2bf(v0.y * i0);
        o0.z = f2bf(v0.z * i0); o0.w = f2bf(v0.w * i0);
        o1.x = f2bf(v1.x * i1); o1.y = f2bf(v1.y * i1);
        o1.z = f2bf(v1.z * i1); o1.w = f2bf(v1.w * i1);
        reinterpret_cast<ushort4*>(znb + (size_t)r0 * D_DIM)[lane] = o0;
        reinterpret_cast<ushort4*>(znb + (size_t)r1 * D_DIM)[lane] = o1;
    }
}

// class-mean partial sums from bf16 znb gather. grid (256 classes, 2 segs).
// wave handles 2 rows/inst (half-wave per row), ILP-4 -> 8 rows in flight.
__global__ __launch_bounds__(256)
void k_meansC(const __hip_bfloat16* __restrict__ znb, const int* __restrict__ cursor,
              const int* __restrict__ order, float* __restrict__ meanp)
{
    __shared__ float red[4][D_DIM];
    const int c = blockIdx.x, sgt = blockIdx.y;
    const int t = threadIdx.x, lane = t & 63, w = t >> 6;
    const int h = lane >> 5, l31 = lane & 31;
    const int cnt = cursor[c];
    const int chunk = (cnt + 1) >> 1;
    const int beg = sgt * chunk;
    const int end = min(beg + chunk, cnt);
    const int* ord = order + c * BUCKET;

    float acc[8] = {};
    int base = beg;
    for (; base + 32 <= end; base += 32) {
        #pragma unroll
        for (int u = 0; u < 4; ++u) {
            const int r = ord[base + w * 8 + u * 2 + h];
            const ushort8v v = *reinterpret_cast<const ushort8v*>(
                znb + (size_t)r * D_DIM + l31 * 8);
            #pragma unroll
            for (int j = 0; j < 8; ++j) acc[j] += bf2f(v[j]);
        }
    }
    if (base < end) {   // masked tail
        #pragma unroll
        for (int u = 0; u < 4; ++u) {
            const int ri = base + w * 8 + u * 2 + h;
            const bool ok = ri < end;
            const int r = ord[ok ? ri : beg];
            const ushort8v v = *reinterpret_cast<const ushort8v*>(
                znb + (size_t)r * D_DIM + l31 * 8);
            const float sc = ok ? 1.0f : 0.0f;
            #pragma unroll
            for (int j = 0; j < 8; ++j) acc[j] += bf2f(v[j]) * sc;
        }
    }
    #pragma unroll
    for (int j = 0; j < 8; ++j) acc[j] += __shfl_xor(acc[j], 32, 64);
    if (h == 0) {
        #pragma unroll
        for (int j = 0; j < 8; ++j) red[w][l31 * 8 + j] = acc[j];
    }
    __syncthreads();
    // 256 threads: one dim each
    const float s = red[0][t] + red[1][t] + red[2][t] + red[3][t];
    meanp[((size_t)sgt * C_CLS + c) * D_DIM + t] = s;
}

// reduce 2 segments -> bf16 means
__global__ __launch_bounds__(256)
void k_means2C(const float* __restrict__ meanp, const int* __restrict__ cursor,
               __hip_bfloat16* __restrict__ means)
{
    const int tid = blockIdx.x * 256 + threadIdx.x;   // 64 blocks -> 16384
    const int c = tid >> 6, l = tid & 63;
    const float invc = 1.0f / fmaxf((float)cursor[c], 1.0f);
    const float4 s0 = *reinterpret_cast<const float4*>(meanp + (size_t)c * D_DIM + 4 * l);
    const float4 s1 = *reinterpret_cast<const float4*>(meanp + (size_t)(C_CLS + c) * D_DIM + 4 * l);
    ushort4 o;
    o.x = f2bf((s0.x + s1.x) * invc);
    o.y = f2bf((s0.y + s1.y) * invc);
    o.z = f2bf((s0.z + s1.z) * invc);
    o.w = f2bf((s0.w + s1.w) * invc);
    *reinterpret_cast<ushort4*>(means + (size_t)c * D_DIM + 4 * l) = o;
}

// MFMA GEMM + in-register LSE. 1024 blocks x 256 thr (4 waves).
// Tile 128 rows x 256 cls, BK=32 (8 kts). A/B staged via global_load_lds with
// inverse-swizzled source; ds_reads use key ((l31>>1)&3)<<4 -> bank floor.
// LDS: A dbuf 2x8K @0, B dbuf 2x16K @16K, labs @48K, expsum @49.5K, proto @50.5K.
__global__ __launch_bounds__(256, 2)
void k_mainC(const __hip_bfloat16* __restrict__ znb, const int* __restrict__ labels,
             const __hip_bfloat16* __restrict__ means, float* __restrict__ out)
{
    __shared__ char smem[51712];
    int*   labs   = reinterpret_cast<int*>(smem + 49152);    // [128]
    float* expsum = reinterpret_cast<float*>(smem + 49664);  // [128][2]
    float* proto  = reinterpret_cast<float*>(smem + 50688);  // [128]

    const int t    = threadIdx.x;
    const int lane = t & 63;
    const int w    = t >> 6;
    const int wr   = w >> 1, wc = w & 1;
    const int l31  = lane & 31;
    const int g    = lane >> 5;
    const int g16  = g << 4;
    const int row0 = blockIdx.x * 128;

    const char* znbB   = (const char*)znb;
    const char* meansB = (const char*)means;

    // stage-side swizzle key (row = ..*16 + (lane>>2))
    const int skey = ((lane >> 3) & 3) << 4;
    const int sc   = ((lane & 3) << 4) ^ skey;
    // read-side key (row/cls = ..*32 + l31)
    const int rk   = ((l31 >> 1) & 3) << 4;

    auto A_STAGE = [&](int kt, int buf) {
        #pragma unroll
        for (int i = 0; i < 2; ++i) {
            const int row = w * 32 + i * 16 + (lane >> 2);
            gload_lds16(znbB + (size_t)(row0 + row) * 512 + kt * 64 + sc,
                        smem + buf * 8192 + (w * 2 + i) * 1024);
        }
    };
    auto B_STAGE = [&](int kt, int buf) {
        #pragma unroll
        for (int j = 0; j < 4; ++j) {
            const int cls = w * 64 + j * 16 + (lane >> 2);
            gload_lds16(meansB + (size_t)cls * 512 + kt * 64 + sc,
                        smem + 16384 + buf * 16384 + (w * 4 + j) * 1024);
        }
    };

    f32x16 acc[2][4] = {};
    auto COMPUTE = [&](int buf) {
        const char* ab = smem + buf * 8192;
        const char* bb = smem + 16384 + buf * 16384;
        #pragma unroll
        for (int ks = 0; ks < 2; ++ks) {
            const int co = (ks * 32 + g16) ^ rk;
            const short8 a0 = *reinterpret_cast<const short8*>(ab + (wr * 64 + l31) * 64 + co);
            const short8 a1 = *reinterpret_cast<const short8*>(ab + (wr * 64 + 32 + l31) * 64 + co);
            short8 bfr[4];
            #pragma unroll
            for (int n = 0; n < 4; ++n)
                bfr[n] = *reinterpret_cast<const short8*>(
                    bb + (wc * 128 + n * 32 + l31) * 64 + co);
            #pragma unroll
            for (int n = 0; n < 4; ++n) {
                acc[0][n] = __builtin_amdgcn_mfma_f32_32x32x16_bf16(a0, bfr[n], acc[0][n], 0, 0, 0);
                acc[1][n] = __builtin_amdgcn_mfma_f32_32x32x16_bf16(a1, bfr[n], acc[1][n], 0, 0, 0);
            }
        }
    };

    // prologue: labels + first tiles
    if (t < 128) {
        const int gr = row0 + t;
        labs[t] = labels[(gr < N_ROWS) ? gr : gr - N_ROWS];
    }
    A_STAGE(0, 0);
    B_STAGE(0, 0);
    __syncthreads();

    #pragma unroll
    for (int kt = 0; kt < 8; ++kt) {
        if (kt < 7) { A_STAGE(kt + 1, (kt + 1) & 1); B_STAGE(kt + 1, (kt + 1) & 1); }
        COMPUTE(kt & 1);
        __syncthreads();       // drains next-buf gloads; one barrier per kt
    }

    // ---- in-register LSE ----
    // rowsum[rt][q]: sum over this wave's 128 cols of exp(sim) for row
    // r = wr*64 + rt*32 + (q&3)+8*(q>>2)+4*g  (row independent of l31).
    float rowsum[2][16];
    #pragma unroll
    for (int rt = 0; rt < 2; ++rt)
        #pragma unroll
        for (int q = 0; q < 16; ++q) {
            float s = __expf(acc[rt][0][q]) + __expf(acc[rt][1][q])
                    + __expf(acc[rt][2][q]) + __expf(acc[rt][3][q]);
            rowsum[rt][q] = s;
        }
    #pragma unroll
    for (int off = 1; off <= 16; off <<= 1) {
        #pragma unroll
        for (int rt = 0; rt < 2; ++rt)
            #pragma unroll
            for (int q = 0; q < 16; ++q)
                rowsum[rt][q] += __shfl_xor(rowsum[rt][q], off, 64);
    }
    if (l31 == 0) {
        #pragma unroll
        for (int rt = 0; rt < 2; ++rt)
            #pragma unroll
            for (int q = 0; q < 16; ++q) {
                const int r = wr * 64 + rt * 32 + (q & 3) + 8 * (q >> 2) + 4 * g;
                expsum[r * 2 + wc] = rowsum[rt][q];
            }
    }
    // proto: unique-lane label match
    #pragma unroll
    for (int rt = 0; rt < 2; ++rt)
        #pragma unroll
        for (int q = 0; q < 16; ++q) {
            const int r = wr * 64 + rt * 32 + (q & 3) + 8 * (q >> 2) + 4 * g;
            const int lab = labs[r];
            #pragma unroll
            for (int n = 0; n < 4; ++n)
                if (lab == wc * 128 + n * 32 + l31) proto[r] = acc[rt][n][q];
        }
    __syncthreads();

    if (t < 128) {
        const float es = expsum[t * 2] + expsum[t * 2 + 1];
        float lp = 2.0f * proto[t] - __logf(es);
        #pragma unroll
        for (int off = 1; off < 64; off <<= 1) lp += __shfl_xor(lp, off, 64);
        if (lane == 0) atomicAdd(out, -lp * (1.0f / (float)TWO_N));
    }
}

// ========================== FALLBACK PATH (round 3, proven) ==========================

__global__ __launch_bounds__(256)
void k_norm_fb(const float* __restrict__ z1, const float* __restrict__ z2,
               float* __restrict__ inv_norm)
{
    const int w = threadIdx.x >> 6, lane = threadIdx.x & 63;
    const int wave = blockIdx.x * 4 + w;
    #pragma unroll 1
    for (int b = 0; b < 4; ++b) {
        int r[4]; float4 v[4]; float s[4];
        #pragma unroll
        for (int j = 0; j < 4; ++j) {
            r[j] = wave + 8192 * (b * 4 + j);
            const float* src = (r[j] < N_ROWS) ? z1 + (size_t)r[j] * D_DIM
                                               : z2 + (size_t)(r[j] - N_ROWS) * D_DIM;
            v[j] = reinterpret_cast<const float4*>(src)[lane];
        }
        #pragma unroll
        for (int j = 0; j < 4; ++j)
            s[j] = v[j].x * v[j].x + v[j].y * v[j].y + v[j].z * v[j].z + v[j].w * v[j].w;
        #pragma unroll
        for (int off = 1; off < 64; off <<= 1) {
            #pragma unroll
            for (int j = 0; j < 4; ++j) s[j] += __shfl_xor(s[j], off, 64);
        }
        if (lane == 0) {
            #pragma unroll
            for (int j = 0; j < 4; ++j)
                inv_norm[r[j]] = 1.0f / fmaxf(sqrtf(s[j]), EPS_NORM);
        }
    }
}

__global__ __launch_bounds__(256)
void k_means_fb(const float* __restrict__ z1, const float* __restrict__ z2,
                const float* __restrict__ inv_norm, const int* __restrict__ cursor,
                const int* __restrict__ order, float* __restrict__ meanp)
{
    __shared__ float4 red4[4][64];
    const int c = blockIdx.x, sgt = blockIdx.y;
    const int lane = threadIdx.x & 63, w = threadIdx.x >> 6;
    const int cnt = cursor[c];
    const int chunk = (cnt + 3) >> 2;
    const int beg = sgt * chunk;
    const int end = min(beg + chunk, cnt);
    const int* ord = order + c * BUCKET;
    float4 acc = {0.f, 0.f, 0.f, 0.f};
    int idx = beg + w;
    for (; idx + 12 < end; idx += 16) {
        int rr[4]; float4 v[4]; float iv[4];
        #pragma unroll
        for (int u = 0; u < 4; ++u) rr[u] = ord[idx + 4 * u];
        #pragma unroll
        for (int u = 0; u < 4; ++u) {
            const float* src = (rr[u] < N_ROWS) ? z1 + (size_t)rr[u] * D_DIM
                                                : z2 + (size_t)(rr[u] - N_ROWS) * D_DIM;
            v[u] = reinterpret_cast<const float4*>(src)[lane];
            iv[u] = inv_norm[rr[u]];
        }
        #pragma unroll
        for (int u = 0; u < 4; ++u) {
            acc.x = fmaf(v[u].x, iv[u], acc.x);
            acc.y = fmaf(v[u].y, iv[u], acc.y);
            acc.z = fmaf(v[u].z, iv[u], acc.z);
            acc.w = fmaf(v[u].w, iv[u], acc.w);
        }
    }
    for (; idx < end; idx += 4) {
        const int r1 = ord[idx];
        const float* src = (r1 < N_ROWS) ? z1 + (size_t)r1 * D_DIM
                                         : z2 + (size_t)(r1 - N_ROWS) * D_DIM;
        const float4 v = reinterpret_cast<const float4*>(src)[lane];
        const float iv = inv_norm[r1];
        acc.x = fmaf(v.x, iv, acc.x); acc.y = fmaf(v.y, iv, acc.y);
        acc.z = fmaf(v.z, iv, acc.z); acc.w = fmaf(v.w, iv, acc.w);
    }
    red4[w][lane] = acc;
    __syncthreads();
    if (w == 0) {
        const float4 a0 = red4[0][lane], a1 = red4[1][lane];
        const float4 a2 = red4[2][lane], a3 = red4[3][lane];
        float4 o;
        o.x = a0.x + a1.x + a2.x + a3.x;  o.y = a0.y + a1.y + a2.y + a3.y;
        o.z = a0.z + a1.z + a2.z + a3.z;  o.w = a0.w + a1.w + a2.w + a3.w;
        *reinterpret_cast<float4*>(meanp + ((size_t)c * 4 + sgt) * D_DIM + 4 * lane) = o;
    }
}

__global__ __launch_bounds__(256)
void k_means2_fb(const float* __restrict__ meanp, const int* __restrict__ cursor,
                 __hip_bfloat16* __restrict__ means)
{
    const int tid = blockIdx.x * 256 + threadIdx.x;
    const int c = tid >> 6, l = tid & 63;
    const float invc = 1.0f / fmaxf((float)cursor[c], 1.0f);
    const float4 s0 = *reinterpret_cast<const float4*>(meanp + ((size_t)c * 4 + 0) * D_DIM + 4 * l);
    const float4 s1 = *reinterpret_cast<const float4*>(meanp + ((size_t)c * 4 + 1) * D_DIM + 4 * l);
    const float4 s2 = *reinterpret_cast<const float4*>(meanp + ((size_t)c * 4 + 2) * D_DIM + 4 * l);
    const float4 s3 = *reinterpret_cast<const float4*>(meanp + ((size_t)c * 4 + 3) * D_DIM + 4 * l);
    ushort4 o;
    o.x = f2bf((s0.x + s1.x + s2.x + s3.x) * invc);
    o.y = f2bf((s0.y + s1.y + s2.y + s3.y) * invc);
    o.z = f2bf((s0.z + s1.z + s2.z + s3.z) * invc);
    o.w = f2bf((s0.w + s1.w + s2.w + s3.w) * invc);
    *reinterpret_cast<ushort4*>(means + (size_t)c * D_DIM + 4 * l) = o;
}

__global__ __launch_bounds__(256, 2)
void k_main_fb(const float* __restrict__ z1, const float* __restrict__ z2,
               const float* __restrict__ inv_norm, const int* __restrict__ labels,
               const __hip_bfloat16* __restrict__ means, float* __restrict__ lossp)
{
    __shared__ char smem[65536];
    const int t    = threadIdx.x;
    const int lane = t & 63;
    const int w    = t >> 6;
    const int wr   = w >> 1, wc = w & 1;
    const int l31  = lane & 31;
    const int g16  = (lane >> 5) << 4;
    const int row0 = blockIdx.x * 128;

    const int a_row  = t >> 1;
    const int a_half = t & 1;
    const int grow   = row0 + a_row;
    const float* zsrc = (grow < N_ROWS) ? z1 + (size_t)grow * D_DIM
                                        : z2 + (size_t)(grow - N_ROWS) * D_DIM;
    const float inv_a = inv_norm[grow];
    const int  a_key  = (((a_row & 3) ^ ((a_row >> 3) & 3)) << 4);
    char* const aw0 = smem + a_row * 64 + ((a_half * 32 + 0)  ^ a_key);
    char* const aw1 = smem + a_row * 64 + ((a_half * 32 + 16) ^ a_key);

    const int rkey = (((l31 & 3) ^ ((l31 >> 3) & 3)) << 4);
    f32x16 acc[2][4] = {};
    float4 pre[4];

    auto A_LOAD = [&](int kt) {
        const float4* s = reinterpret_cast<const float4*>(zsrc + kt * 32 + a_half * 16);
        pre[0] = s[0]; pre[1] = s[1]; pre[2] = s[2]; pre[3] = s[3];
    };
    auto A_WRITE = [&](int buf) {
        ushort8v o1, o2;
        o1[0] = f2bf(pre[0].x * inv_a); o1[1] = f2bf(pre[0].y * inv_a);
        o1[2] = f2bf(pre[0].z * inv_a); o1[3] = f2bf(pre[0].w * inv_a);
        o1[4] = f2bf(pre[1].x * inv_a); o1[5] = f2bf(pre[1].y * inv_a);
        o1[6] = f2bf(pre[1].z * inv_a); o1[7] = f2bf(pre[1].w * inv_a);
        o2[0] = f2bf(pre[2].x * inv_a); o2[1] = f2bf(pre[2].y * inv_a);
        o2[2] = f2bf(pre[2].z * inv_a); o2[3] = f2bf(pre[2].w * inv_a);
        o2[4] = f2bf(pre[3].x * inv_a); o2[5] = f2bf(pre[3].y * inv_a);
        o2[6] = f2bf(pre[3].z * inv_a); o2[7] = f2bf(pre[3].w * inv_a);
        *reinterpret_cast<ushort8v*>(aw0 + buf * 8192) = o1;
        *reinterpret_cast<ushort8v*>(aw1 + buf * 8192) = o2;
    };
    auto B_STAGE = [&](int kt, int buf) {
        #pragma unroll
        for (int q = 0; q < 4; ++q) {
            const int gg  = q * 256 + t;
            const int c   = gg >> 2;
            const int cb  = (gg & 3) << 4;
            const int key = (((c & 3) ^ ((c >> 3) & 3)) << 4);
            gload_lds16((const char*)means + (size_t)c * 512 + kt * 64 + (cb ^ key),
                        smem + 16384 + buf * 16384 + q * 4096 + w * 1024);
        }
    };
    auto COMPUTE = [&](int buf) {
        const char* ab = smem + buf * 8192;
        const char* bb = smem + 16384 + buf * 16384;
        #pragma unroll
        for (int ks = 0; ks < 2; ++ks) {
            const int cb = (ks * 32 + g16) ^ rkey;
            const short8 a0 = *reinterpret_cast<const short8*>(ab + (wr * 64 + l31) * 64 + cb);
            const short8 a1 = *reinterpret_cast<const short8*>(ab + (wr * 64 + 32 + l31) * 64 + cb);
            short8 bfr[4];
            #pragma unroll
            for (int n = 0; n < 4; ++n)
                bfr[n] = *reinterpret_cast<const short8*>(bb + (wc * 128 + n * 32 + l31) * 64 + cb);
            #pragma unroll
            for (int n = 0; n < 4; ++n) {
                acc[0][n] = __builtin_amdgcn_mfma_f32_32x32x16_bf16(a0, bfr[n], acc[0][n], 0, 0, 0);
                acc[1][n] = __builtin_amdgcn_mfma_f32_32x32x16_bf16(a1, bfr[n], acc[1][n], 0, 0, 0);
            }
        }
    };

    B_STAGE(0, 0);
    A_LOAD(0);
    A_WRITE(0);
    #pragma unroll
    for (int kt = 0; kt < 8; ++kt) {
        __syncthreads();
        if (kt < 7) { B_STAGE(kt + 1, (kt + 1) & 1); A_LOAD(kt + 1); }
        COMPUTE(kt & 1);
        if (kt < 7) A_WRITE((kt + 1) & 1);
    }
    __syncthreads();

    float* simf = reinterpret_cast<float*>(smem);
    float partial = 0.0f;
    for (int rhalf = 0; rhalf < 2; ++rhalf) {
        if (wr == rhalf) {
            #pragma unroll
            for (int rt = 0; rt < 2; ++rt)
                #pragma unroll
                for (int n = 0; n < 4; ++n)
                    #pragma unroll
                    for (int q = 0; q < 16; ++q) {
                        const int row64 = rt * 32 + (q & 3) + 8 * (q >> 2) + 4 * (lane >> 5);
                        const int col   = wc * 128 + n * 32 + l31;
                        simf[row64 * 256 + col] = acc[rt][n][q];
                    }
        }
        __syncthreads();
        #pragma unroll 1
        for (int i = 0; i < 16; ++i) {
            const int rl    = w * 16 + i;
            const int growr = row0 + rhalf * 64 + rl;
            float s = __expf(simf[rl * 256 + lane])       + __expf(simf[rl * 256 + 64 + lane])
                    + __expf(simf[rl * 256 + 128 + lane]) + __expf(simf[rl * 256 + 192 + lane]);
            #pragma unroll
            for (int off = 32; off; off >>= 1) s += __shfl_down(s, off, 64);
            const int lab = labels[(growr < N_ROWS) ? growr : growr - N_ROWS];
            const float sp = simf[rl * 256 + lab];
            if (lane == 0) partial += 2.0f * sp - logf(s);
        }
        __syncthreads();
    }
    if (lane == 0) simf[w] = partial;
    __syncthreads();
    if (t == 0) lossp[blockIdx.x] = simf[0] + simf[1] + simf[2] + simf[3];
}

__global__ __launch_bounds__(256)
void k_final_fb(const float* __restrict__ lossp, float* __restrict__ out)
{
    __shared__ float red[4];
    const int t = threadIdx.x, lane = t & 63, w = t >> 6;
    float s = lossp[t] + lossp[t + 256] + lossp[t + 512] + lossp[t + 768];
    #pragma unroll
    for (int off = 32; off; off >>= 1) s += __shfl_down(s, off, 64);
    if (lane == 0) red[w] = s;
    __syncthreads();
    if (t == 0) out[0] = -(red[0] + red[1] + red[2] + red[3]) / (float)TWO_N;
}

// ========================== host ==========================
extern "C" void kernel_launch(void* const* d_in, const int* in_sizes, int n_in,
                              void* d_out, int out_size, void* d_ws, size_t ws_size,
                              hipStream_t stream)
{
    const float* z1     = (const float*)d_in[0];
    const float* z2     = (const float*)d_in[1];
    const int*   labels = (const int*)d_in[2];
    float* out = (float*)d_out;
    char*  ws  = (char*)d_ws;

    if (ws_size >= CW_NEED) {
        int*   cursor = (int*)  (ws + CW_CURSOR);
        float* meanp  = (float*)(ws + CW_MEANP);
        int*   order  = (int*)  (ws + CW_ORDER);
        __hip_bfloat16* means = (__hip_bfloat16*)(ws + CW_MEANS);
        __hip_bfloat16* znb   = (__hip_bfloat16*)(ws + CW_ZNB);

        hipMemsetAsync(ws, 0, 4096, stream);              // cursors
        hipMemsetAsync(d_out, 0, sizeof(float), stream);  // atomic loss target

        hipLaunchKernelGGL(k_norm,    dim3(2048), dim3(256), 0, stream, z1, z2, znb);
        hipLaunchKernelGGL(k_scatter, dim3(64),   dim3(256), 0, stream, labels, cursor, order);
        hipLaunchKernelGGL(k_meansC,  dim3(C_CLS, 2), dim3(256), 0, stream, znb, cursor, order, meanp);
        hipLaunchKernelGGL(k_means2C, dim3(64),   dim3(256), 0, stream, meanp, cursor, means);
        hipLaunchKernelGGL(k_mainC,   dim3(TWO_N / 128), dim3(256), 0, stream, znb, labels, means, out);
    } else {
        int*   cursor   = (int*)  (ws + FW_CURSOR);
        float* lossp    = (float*)(ws + FW_LOSSP);
        float* inv_norm = (float*)(ws + FW_INVN);
        int*   order    = (int*)  (ws + FW_ORDER);
        float* meanp    = (float*)(ws + FW_MEANP);
        __hip_bfloat16* means = (__hip_bfloat16*)(ws + FW_MEANS);

        hipMemsetAsync(ws, 0, 4096, stream);

        hipLaunchKernelGGL(k_norm_fb,   dim3(2048), dim3(256), 0, stream, z1, z2, inv_norm);
        hipLaunchKernelGGL(k_scatter,   dim3(64),   dim3(256), 0, stream, labels, cursor, order);
        hipLaunchKernelGGL(k_means_fb,  dim3(C_CLS, 4), dim3(256), 0, stream, z1, z2, inv_norm, cursor, order, meanp);
        hipLaunchKernelGGL(k_means2_fb, dim3(64),   dim3(256), 0, stream, meanp, cursor, means);
        hipLaunchKernelGGL(k_main_fb,   dim3(TWO_N / 128), dim3(256), 0, stream, z1, z2, inv_norm, labels, means, lossp);
        hipLaunchKernelGGL(k_final_fb,  dim3(1),    dim3(256), 0, stream, lossp, out);
    }
}